// Round 10
// baseline (375.797 us; speedup 1.0000x reference)
//
#include <hip/hip_runtime.h>

#define MUL 16
#define NTILE 30          // 12 s-tiles + 12 pq-tiles + 6 t-tiles
#define NCHUNK 6

typedef __bf16 bf16x8 __attribute__((ext_vector_type(8)));
typedef float  f32x2  __attribute__((ext_vector_type(2)));
typedef float  f32x4  __attribute__((ext_vector_type(4)));

// Group schedule: 24 groups g, each = (u_g, vstart_g), covering 8 pair slots
// j=0..7 with v = vstart+j (valid while v<=15; pads have zero B columns).
//   u<=7: two groups: g=2u+h -> vstart = u + 8h
//   u>=8: one group:  g=16+(u-8) -> vstart = u
__device__ __forceinline__ void group_uvs(int g, int& u, int& vs) {
    if (g < 16) { u = g >> 1; vs = u + ((g & 1) << 3); }
    else        { u = g - 8;  vs = u; }
}

// ---------------------------------------------------------------------------
// prep: one thread per 16-B B-fragment (tile,lane).  (unchanged)
// ---------------------------------------------------------------------------
__global__ void prep_weights(const float* __restrict__ w000,
                             const float* __restrict__ w101,
                             const float* __restrict__ w110,
                             const float* __restrict__ w112,
                             __bf16* __restrict__ wt) {
    const int gid = blockIdx.x * 256 + threadIdx.x;
    if (gid >= NTILE * 64) return;
    const int T = gid >> 6, lane = gid & 63;
    const int q = lane >> 4, w = lane & 15;

    const float A000   = 0.044194173824159216f;   // sqrt(1/(2*16*16))
    const float A110   = 0.025515518153991442f;   // A000/sqrt(3)
    const float A101   = 0.0625f;
    const float A112C1 = 0.044194173824159216f;   // A112/sqrt(10)

    bf16x8 frag = {};
    if (T < 12) {
        const int c = T >> 1, h = T & 1;
        int u, vs; group_uvs(4 * c + q, u, vs);
#pragma unroll
        for (int i = 0; i < 4; ++i) {
            const int v = vs + 4 * h + i;
            if (v < 16) {
                const int uvw = (u * MUL + v) * MUL + w;
                const int vuw = (v * MUL + u) * MUL + w;
                float f000, f110;
                if (u == v) { f000 = A000 * w000[uvw]; f110 = A110 * w110[uvw]; }
                else        { f000 = A000 * (w000[uvw] + w000[vuw]);
                              f110 = A110 * (w110[uvw] + w110[vuw]); }
                frag[2 * i]     = (__bf16)f000;
                frag[2 * i + 1] = (__bf16)f110;
            }
        }
    } else if (T < 24) {
        const int c = (T - 12) >> 1, h = (T - 12) & 1;
        int u, vs; group_uvs(4 * c + q, u, vs);
#pragma unroll
        for (int i = 0; i < 4; ++i) {
            const int v = vs + 4 * h + i;
            if (v < 16) {
                const int uvw = (u * MUL + v) * MUL + w;
                const int vuw = (v * MUL + u) * MUL + w;
                frag[2 * i]     = (__bf16)(A101 * w101[uvw]);
                frag[2 * i + 1] = (__bf16)((u == v) ? 0.f : A101 * w101[vuw]);
            }
        }
    } else {
        const int c = T - 24;
        int u, vs; group_uvs(4 * c + q, u, vs);
#pragma unroll
        for (int e = 0; e < 8; ++e) {
            const int v = vs + e;
            if (v < 16) {
                const int uvw = (u * MUL + v) * MUL + w;
                const int vuw = (v * MUL + u) * MUL + w;
                const float f112 = (u == v) ? A112C1 * w112[uvw]
                                            : A112C1 * (w112[uvw] + w112[vuw]);
                frag[e] = (__bf16)f112;
            }
        }
    }
    ((bf16x8*)wt)[T * 64 + lane] = frag;
}

// ---------------------------------------------------------------------------
// Main: 256-thread blocks = 4 INDEPENDENT waves; each wave pipelines TWO
// 16-node tiles (A then B).  B's 32 global loads are issued mid-compute-A so
// their HBM latency hides under chunks 3-5 + epilogue A (T14 split).  All
// LDS slices are wave-private -> NO __syncthreads; within-wave producer->
// consumer ordering via s_waitcnt lgkmcnt(0) + sched_barrier (rule #18).
// __launch_bounds__(256,3): the proven-clean VGPR budget (r9: 84 VGPR, zero
// spill; (256,4)/waves_per_eu attr -> 64-cap spill loop, r5-r7).
// Per-wave slice (2304 f32) is a UNION: xq quads (16x68) during compute,
// epilogue image (16x144) after; tile B re-stages into the same slice.
// ---------------------------------------------------------------------------
#define SQ3f  1.7320508075688772f
#define ISQ3f 0.5773502691896258f

#define WAIT_LDS() do {                                     \
        asm volatile("s_waitcnt lgkmcnt(0)" ::: "memory");  \
        __builtin_amdgcn_sched_barrier(0);                  \
    } while (0)

template<int J>
__device__ __forceinline__ void do_pair(int vs, const float* __restrict__ xrow,
        const float4 xu,
        bf16x8& fS, bf16x8& f0, bf16x8& f1, bf16x8& f2,
        bf16x8& t0, bf16x8& t1, bf16x8& t2, bf16x8& t3, bf16x8& t4) {
    int v = vs + J;
    v = v < 15 ? v : 15;                              // pads: B cols are zero
    const float4 xv = *(const float4*)(xrow + 4 * v);

    const f32x2 U01 = {xu.x, xu.y};   // (x0u, a0u)
    const f32x2 U23 = {xu.z, xu.w};   // (a1u, a2u)
    const f32x2 U10 = {xu.y, xu.x};
    const f32x2 V01 = {xv.x, xv.y};
    const f32x2 V23 = {xv.z, xv.w};
    const f32x2 V10 = {xv.y, xv.x};
    const f32x2 V32 = {xv.w, xv.z};

    const f32x2 P1 = U01 * V01;       // (s0,   o00)
    const f32x2 P2 = U23 * V23;       // (o11,  o22)
    const f32x2 P3 = U01 * V23;       // (f1vu, o02)
    const f32x2 P4 = U23 * V01;       // (f1uv, o20)
    const f32x2 P5 = U01 * V32;       // (f2vu, o01)
    const f32x2 P6 = U23 * V10;       // (o10,  f2uv)
    const f32x2 P7 = U23 * V32;       // (o12,  o21)
    const f32x2 P8 = U10 * V01;       // (f0uv, f0vu)

    const float o00 = P1[1], o11 = P2[0], o22 = P2[1];
    const float s1 = (o00 + o11) + o22;

    constexpr int s2 = (J & 3) * 2;
    fS[s2]     = (__bf16)P1[0];  fS[s2 + 1] = (__bf16)s1;
    f0[s2]     = (__bf16)P8[0];  f0[s2 + 1] = (__bf16)P8[1];
    f1[s2]     = (__bf16)P4[0];  f1[s2 + 1] = (__bf16)P3[0];
    f2[s2]     = (__bf16)P6[1];  f2[s2 + 1] = (__bf16)P5[0];
    t0[J] = (__bf16)(P5[1] + P6[0]);
    t1[J] = (__bf16)(P3[1] + P4[1]);
    t2[J] = (__bf16)(P7[0] + P7[1]);
    t3[J] = (__bf16)(o00 - o11);
    t4[J] = (__bf16)(SQ3f * o22 - ISQ3f * s1);
}

// One K-chunk (compile-time c) of the per-wave MFMA schedule.
#define DO_CHUNK(cc)                                                          \
    {                                                                         \
        constexpr int c = (cc);                                               \
        const bf16x8 bS0 = wb[(2 * c) * 64 + lane];                           \
        const bf16x8 bS1 = wb[(2 * c + 1) * 64 + lane];                       \
        const bf16x8 bP0 = wb[(12 + 2 * c) * 64 + lane];                      \
        const bf16x8 bP1 = wb[(13 + 2 * c) * 64 + lane];                      \
        const bf16x8 bT  = wb[(24 + c) * 64 + lane];                          \
        int u, vs;                                                            \
        if (c < 4) { u = 2 * c + (q >> 1); vs = u + ((q & 1) << 3); }         \
        else       { u = 4 * c - 8 + q;    vs = u; }                          \
        const float4 xu = *(const float4*)(xrow + 4 * u);                     \
        bf16x8 t0 = {}, t1 = {}, t2 = {}, t3 = {}, t4 = {};                   \
        {                                                                     \
            bf16x8 fS, f0, f1, f2;                                            \
            do_pair<0>(vs, xrow, xu, fS, f0, f1, f2, t0, t1, t2, t3, t4);     \
            do_pair<1>(vs, xrow, xu, fS, f0, f1, f2, t0, t1, t2, t3, t4);     \
            do_pair<2>(vs, xrow, xu, fS, f0, f1, f2, t0, t1, t2, t3, t4);     \
            do_pair<3>(vs, xrow, xu, fS, f0, f1, f2, t0, t1, t2, t3, t4);     \
            accS  = __builtin_amdgcn_mfma_f32_16x16x32_bf16(fS, bS0, accS,  0, 0, 0); \
            accP0 = __builtin_amdgcn_mfma_f32_16x16x32_bf16(f0, bP0, accP0, 0, 0, 0); \
            accP1 = __builtin_amdgcn_mfma_f32_16x16x32_bf16(f1, bP0, accP1, 0, 0, 0); \
            accP2 = __builtin_amdgcn_mfma_f32_16x16x32_bf16(f2, bP0, accP2, 0, 0, 0); \
        }                                                                     \
        {                                                                     \
            bf16x8 fS, f0, f1, f2;                                            \
            do_pair<4>(vs, xrow, xu, fS, f0, f1, f2, t0, t1, t2, t3, t4);     \
            do_pair<5>(vs, xrow, xu, fS, f0, f1, f2, t0, t1, t2, t3, t4);     \
            do_pair<6>(vs, xrow, xu, fS, f0, f1, f2, t0, t1, t2, t3, t4);     \
            do_pair<7>(vs, xrow, xu, fS, f0, f1, f2, t0, t1, t2, t3, t4);     \
            accS  = __builtin_amdgcn_mfma_f32_16x16x32_bf16(fS, bS1, accS,  0, 0, 0); \
            accP0 = __builtin_amdgcn_mfma_f32_16x16x32_bf16(f0, bP1, accP0, 0, 0, 0); \
            accP1 = __builtin_amdgcn_mfma_f32_16x16x32_bf16(f1, bP1, accP1, 0, 0, 0); \
            accP2 = __builtin_amdgcn_mfma_f32_16x16x32_bf16(f2, bP1, accP2, 0, 0, 0); \
        }                                                                     \
        accT0 = __builtin_amdgcn_mfma_f32_16x16x32_bf16(t0, bT, accT0, 0, 0, 0); \
        accT1 = __builtin_amdgcn_mfma_f32_16x16x32_bf16(t1, bT, accT1, 0, 0, 0); \
        accT2 = __builtin_amdgcn_mfma_f32_16x16x32_bf16(t2, bT, accT2, 0, 0, 0); \
        accT3 = __builtin_amdgcn_mfma_f32_16x16x32_bf16(t3, bT, accT3, 0, 0, 0); \
        accT4 = __builtin_amdgcn_mfma_f32_16x16x32_bf16(t4, bT, accT4, 0, 0, 0); \
    }

#define EPILOGUE(nodeBase)                                                    \
    {                                                                         \
        _Pragma("unroll")                                                     \
        for (int r = 0; r < 4; ++r) {                                         \
            float* eb = sw + (q * 4 + r) * 144;                               \
            eb[m]              = accS[r];                                     \
            eb[16 + 3 * m + 0] = accP0[r];                                    \
            eb[16 + 3 * m + 1] = accP1[r];                                    \
            eb[16 + 3 * m + 2] = accP2[r];                                    \
            eb[64 + 5 * m + 0] = accT0[r];                                    \
            eb[64 + 5 * m + 1] = accT1[r];                                    \
            eb[64 + 5 * m + 2] = accT2[r];                                    \
            eb[64 + 5 * m + 3] = accT3[r];                                    \
            eb[64 + 5 * m + 4] = accT4[r];                                    \
        }                                                                     \
        WAIT_LDS();                                                           \
        const float4* ep4 = (const float4*)sw;                                \
        float4* ob4 = (float4*)(out + (nodeBase) * 144);                      \
        _Pragma("unroll")                                                     \
        for (int l = 0; l < 9; ++l)                                           \
            ob4[l * 64 + lane] = ep4[l * 64 + lane];                          \
    }

__launch_bounds__(256, 3)
__global__ void tsq_kernel(const float* __restrict__ feats,
                           const float* __restrict__ msgs,
                           const __bf16* __restrict__ wtiles,
                           float* __restrict__ out) {
    // per-wave slice: UNION of xq (16 x 68 f32) and epilogue image (16 x 144)
    __shared__ __align__(16) float smem[4][2304];

    const int tid  = threadIdx.x;
    const int lane = tid & 63;
    const int wid  = tid >> 6;
    float* sw = smem[wid];

    const int m = lane & 15, q = lane >> 4;       // also staging roles (v, g)
    const float* xrow = sw + m * 68;
    const bf16x8* wb = (const bf16x8*)wtiles;

    const long long nodeA = (long long)blockIdx.x * 128 + wid * 16;
    const long long nodeB = nodeA + 64;

    // ---- stage tile A: thread (q*4+k, m) builds one quad ----
#pragma unroll
    for (int k = 0; k < 4; ++k) {
        const int nd = q * 4 + k;
        const float* fp = feats + (nodeA + nd) * 64;
        const float* mp = msgs  + (nodeA + nd) * 64;
        float4 qd;
        qd.x = fp[m]          + mp[m];
        qd.y = fp[16 + 3 * m] + mp[16 + 3 * m];
        qd.z = fp[17 + 3 * m] + mp[17 + 3 * m];
        qd.w = fp[18 + 3 * m] + mp[18 + 3 * m];
        *(float4*)&sw[nd * 68 + 4 * m] = qd;
    }
    WAIT_LDS();

    f32x4 accS  = {0.f, 0.f, 0.f, 0.f};
    f32x4 accP0 = {0.f, 0.f, 0.f, 0.f};
    f32x4 accP1 = {0.f, 0.f, 0.f, 0.f};
    f32x4 accP2 = {0.f, 0.f, 0.f, 0.f};
    f32x4 accT0 = {0.f, 0.f, 0.f, 0.f};
    f32x4 accT1 = {0.f, 0.f, 0.f, 0.f};
    f32x4 accT2 = {0.f, 0.f, 0.f, 0.f};
    f32x4 accT3 = {0.f, 0.f, 0.f, 0.f};
    f32x4 accT4 = {0.f, 0.f, 0.f, 0.f};

    DO_CHUNK(0)
    DO_CHUNK(1)
    DO_CHUNK(2)

    // ---- issue tile B's global loads NOW: latency hides under chunks 3-5
    //      and epilogue A (T14 async-stage split) ----
    float4 fB[4], mB[4];
#pragma unroll
    for (int k = 0; k < 4; ++k) {
        const int nd = q * 4 + k;
        const float* fp = feats + (nodeB + nd) * 64;
        const float* mp = msgs  + (nodeB + nd) * 64;
        fB[k].x = fp[m];          mB[k].x = mp[m];
        fB[k].y = fp[16 + 3 * m]; mB[k].y = mp[16 + 3 * m];
        fB[k].z = fp[17 + 3 * m]; mB[k].z = mp[17 + 3 * m];
        fB[k].w = fp[18 + 3 * m]; mB[k].w = mp[18 + 3 * m];
    }

    DO_CHUNK(3)
    DO_CHUNK(4)
    DO_CHUNK(5)

    // ---- epilogue A (scatter into union, coalesced store) ----
    EPILOGUE(nodeA)

    // ---- stage tile B into the union slice (ep reads retired in-order) ----
#pragma unroll
    for (int k = 0; k < 4; ++k) {
        const int nd = q * 4 + k;
        float4 qd;
        qd.x = fB[k].x + mB[k].x;
        qd.y = fB[k].y + mB[k].y;
        qd.z = fB[k].z + mB[k].z;
        qd.w = fB[k].w + mB[k].w;
        *(float4*)&sw[nd * 68 + 4 * m] = qd;
    }
    WAIT_LDS();

    accS  = (f32x4){0.f, 0.f, 0.f, 0.f};
    accP0 = (f32x4){0.f, 0.f, 0.f, 0.f};
    accP1 = (f32x4){0.f, 0.f, 0.f, 0.f};
    accP2 = (f32x4){0.f, 0.f, 0.f, 0.f};
    accT0 = (f32x4){0.f, 0.f, 0.f, 0.f};
    accT1 = (f32x4){0.f, 0.f, 0.f, 0.f};
    accT2 = (f32x4){0.f, 0.f, 0.f, 0.f};
    accT3 = (f32x4){0.f, 0.f, 0.f, 0.f};
    accT4 = (f32x4){0.f, 0.f, 0.f, 0.f};

    DO_CHUNK(0)
    DO_CHUNK(1)
    DO_CHUNK(2)
    DO_CHUNK(3)
    DO_CHUNK(4)
    DO_CHUNK(5)

    // ---- epilogue B ----
    EPILOGUE(nodeB)
}

extern "C" void kernel_launch(void* const* d_in, const int* in_sizes, int n_in,
                              void* d_out, int out_size, void* d_ws, size_t ws_size,
                              hipStream_t stream) {
    const float* feats = (const float*)d_in[0];
    const float* msgs  = (const float*)d_in[1];
    const float* w000  = (const float*)d_in[2];
    const float* w101  = (const float*)d_in[3];
    const float* w110  = (const float*)d_in[4];
    const float* w112  = (const float*)d_in[5];
    __bf16* wt = (__bf16*)d_ws;                 // 30*64*16 B = 30720 B
    float* out = (float*)d_out;

    const int n = in_sizes[0] / (4 * MUL);      // 131072 nodes

    prep_weights<<<(NTILE * 64 + 255) / 256, 256, 0, stream>>>(w000, w101, w110, w112, wt);
    tsq_kernel<<<n / 128, 256, 0, stream>>>(feats, msgs, wt, out);
}

// Round 11
// 169.068 us; speedup vs baseline: 2.2228x; 2.2228x over previous
//
#include <hip/hip_runtime.h>

#define MUL 16
#define NTILE 27          // 9 s-tiles + 9 pq-tiles + 9 t-tiles
#define NCHUNK 9

typedef __bf16 bf16x8 __attribute__((ext_vector_type(8)));
typedef float  f32x4  __attribute__((ext_vector_type(4)));

// ---------------------------------------------------------------------------
// Circular-distance schedule.  Chunk c (= distance D = c, 0..8) covers the 16
// ordered pairs (u, (u+c)&15).  k-slot (q, e) of each tile:
//   u = (4q + e) & 15, v = (u + c) & 15, parity p = e>>2.
// Each u appears twice per chunk (two q-windows) with OPPOSITE parities, so
// each ordered pair gets exactly one even slot and one odd slot.
// Coverage: c=0 diagonal (16, unfolded); c=1..7: 16 unordered pairs each,
// folded weights; c=8: 8 unordered pairs, each ordered-twice, unfolded.
// Total = 16 + 112 + 8 = 136 pairs, exact.
// ---------------------------------------------------------------------------
__global__ void prep_weights(const float* __restrict__ w000,
                             const float* __restrict__ w101,
                             const float* __restrict__ w110,
                             const float* __restrict__ w112,
                             __bf16* __restrict__ wt) {
    const int gid = blockIdx.x * 256 + threadIdx.x;
    if (gid >= NTILE * 64) return;
    const int T = gid >> 6, lane = gid & 63;
    const int q = lane >> 4, w = lane & 15;
    const int fam = T / 9;          // 0: s, 1: pq, 2: t
    const int c = T % 9;            // distance D

    const float A000   = 0.044194173824159216f;   // sqrt(1/(2*16*16))
    const float A110   = 0.025515518153991442f;   // A000/sqrt(3)
    const float A101   = 0.0625f;
    const float A112C1 = 0.044194173824159216f;   // A112/sqrt(10)

    const bool mid = (c >= 1 && c <= 7);          // folded classes

    bf16x8 frag = {};
#pragma unroll
    for (int e = 0; e < 8; ++e) {
        const int u = (4 * q + e) & 15;
        const int v = (u + c) & 15;
        const int p = e >> 2;
        const int uvw = (u * MUL + v) * MUL + w;
        const int vuw = (v * MUL + u) * MUL + w;
        float val;
        if (fam == 0) {
            val = (p == 0)
                ? A000 * (mid ? (w000[uvw] + w000[vuw]) : w000[uvw])
                : A110 * (mid ? (w110[uvw] + w110[vuw]) : w110[uvw]);
        } else if (fam == 1) {
            val = (p == 0) ? A101 * w101[uvw]
                           : (mid ? A101 * w101[vuw] : 0.f);
        } else {
            val = (p == 0)
                ? A112C1 * (mid ? (w112[uvw] + w112[vuw]) : w112[uvw])
                : 0.f;
        }
        frag[e] = (__bf16)val;
    }
    ((bf16x8*)wt)[T * 64 + lane] = frag;
}

// ---------------------------------------------------------------------------
// Main: 2048 blocks x 256 threads = 4 independent waves x 16 nodes.  Each
// lane (m, q) holds node m's WHOLE row in registers, ROTATED by 4q quads:
//   x0[p]        = x0[(p+4q)&15]
//   x1[3p..3p+2] = x1[(p+4q)&15][0..2]      (flat: (12q+k) mod 48)
// so chunk c uses u at register position j and v at position (j+c)&15 —
// every index compile-time (rule #20).  Loaded straight from global (32 b128;
// 4x q-replication is L1-resident: each instruction covers the full 16-node
// block).  LDS is used ONLY for the epilogue transpose -> LDS pipe drops from
// ~1013 to ~317 cyc/wave-task (was the binding resource at 54 us).
// No barriers: wave-private slices, lgkmcnt(0) orders scatter->readback.
// ---------------------------------------------------------------------------
#define SQ3f  1.7320508075688772f
#define ISQ3f 0.5773502691896258f

#define WAIT_LDS() do {                                     \
        asm volatile("s_waitcnt lgkmcnt(0)" ::: "memory");  \
        __builtin_amdgcn_sched_barrier(0);                  \
    } while (0)

template<int C>
__device__ __forceinline__ void do_chunk(
        const float (&x0)[16], const float (&x1)[48],
        const bf16x8* __restrict__ wb, int lane,
        f32x4& accS, f32x4& accP0, f32x4& accP1, f32x4& accP2,
        f32x4& accT0, f32x4& accT1, f32x4& accT2, f32x4& accT3, f32x4& accT4)
{
    const bf16x8 bS = wb[C * 64 + lane];
    const bf16x8 bP = wb[(9 + C) * 64 + lane];
    const bf16x8 bT = wb[(18 + C) * 64 + lane];

    bf16x8 fS, f0, f1, f2;
    bf16x8 t0 = {}, t1 = {}, t2 = {}, t3 = {}, t4 = {};

    // parity-0 slots (j = 0..3): s0, pq-even, full t features
#pragma unroll
    for (int j = 0; j < 4; ++j) {
        const int vp = (j + C) & 15;
        const float Ux = x0[j],  U0 = x1[3*j],  U1 = x1[3*j+1],  U2 = x1[3*j+2];
        const float Vx = x0[vp], V0 = x1[3*vp], V1 = x1[3*vp+1], V2 = x1[3*vp+2];
        fS[j] = (__bf16)(Ux * Vx);
        f0[j] = (__bf16)(U0 * Vx);
        f1[j] = (__bf16)(U1 * Vx);
        f2[j] = (__bf16)(U2 * Vx);
        const float o00 = U0*V0, o01 = U0*V1, o02 = U0*V2;
        const float o10 = U1*V0, o11 = U1*V1, o12 = U1*V2;
        const float o20 = U2*V0, o21 = U2*V1, o22 = U2*V2;
        t0[j] = (__bf16)(o01 + o10);
        t1[j] = (__bf16)(o02 + o20);
        t2[j] = (__bf16)(o12 + o21);
        t3[j] = (__bf16)(o00 - o11);
        t4[j] = (__bf16)(SQ3f * o22 - ISQ3f * ((o00 + o11) + o22));
    }
    // parity-1 slots (j = 4..7): s1, pq-odd; t slots are zero-weighted
#pragma unroll
    for (int j = 4; j < 8; ++j) {
        const int vp = (j + C) & 15;
        const float Ux = x0[j],  U0 = x1[3*j],  U1 = x1[3*j+1],  U2 = x1[3*j+2];
        const float Vx = x0[vp], V0 = x1[3*vp], V1 = x1[3*vp+1], V2 = x1[3*vp+2];
        fS[j] = (__bf16)(U0*V0 + U1*V1 + U2*V2);
        f0[j] = (__bf16)(V0 * Ux);
        f1[j] = (__bf16)(V1 * Ux);
        f2[j] = (__bf16)(V2 * Ux);
    }

    accS  = __builtin_amdgcn_mfma_f32_16x16x32_bf16(fS, bS, accS,  0, 0, 0);
    accP0 = __builtin_amdgcn_mfma_f32_16x16x32_bf16(f0, bP, accP0, 0, 0, 0);
    accP1 = __builtin_amdgcn_mfma_f32_16x16x32_bf16(f1, bP, accP1, 0, 0, 0);
    accP2 = __builtin_amdgcn_mfma_f32_16x16x32_bf16(f2, bP, accP2, 0, 0, 0);
    accT0 = __builtin_amdgcn_mfma_f32_16x16x32_bf16(t0, bT, accT0, 0, 0, 0);
    accT1 = __builtin_amdgcn_mfma_f32_16x16x32_bf16(t1, bT, accT1, 0, 0, 0);
    accT2 = __builtin_amdgcn_mfma_f32_16x16x32_bf16(t2, bT, accT2, 0, 0, 0);
    accT3 = __builtin_amdgcn_mfma_f32_16x16x32_bf16(t3, bT, accT3, 0, 0, 0);
    accT4 = __builtin_amdgcn_mfma_f32_16x16x32_bf16(t4, bT, accT4, 0, 0, 0);
}

__launch_bounds__(256, 2)
__global__ void tsq_kernel(const float* __restrict__ feats,
                           const float* __restrict__ msgs,
                           const __bf16* __restrict__ wtiles,
                           float* __restrict__ out) {
    __shared__ __align__(16) float smem[4][2304];   // epilogue image only

    const int tid  = threadIdx.x;
    const int lane = tid & 63;
    const int wid  = tid >> 6;
    float* sw = smem[wid];

    const int m = lane & 15, q = lane >> 4;
    const long long waveNode = (long long)blockIdx.x * 64 + wid * 16;
    const float* fp = feats + (waveNode + m) * 64;
    const float* mp = msgs  + (waveNode + m) * 64;

    // ---- load this lane's node row, rotated by 4q, straight from global ----
    float x0[16], x1[48];
#pragma unroll
    for (int k = 0; k < 4; ++k) {
        const int off = (4 * q + 4 * k) & 15;
        const float4 a = *(const float4*)(fp + off);
        const float4 b = *(const float4*)(mp + off);
        x0[4*k+0] = a.x + b.x;
        x0[4*k+1] = a.y + b.y;
        x0[4*k+2] = a.z + b.z;
        x0[4*k+3] = a.w + b.w;
    }
#pragma unroll
    for (int r = 0; r < 12; ++r) {
        int off = 12 * q + 4 * r;
        off = (off >= 48) ? off - 48 : off;
        const float4 a = *(const float4*)(fp + 16 + off);
        const float4 b = *(const float4*)(mp + 16 + off);
        x1[4*r+0] = a.x + b.x;
        x1[4*r+1] = a.y + b.y;
        x1[4*r+2] = a.z + b.z;
        x1[4*r+3] = a.w + b.w;
    }

    f32x4 accS  = {0.f, 0.f, 0.f, 0.f};
    f32x4 accP0 = {0.f, 0.f, 0.f, 0.f};
    f32x4 accP1 = {0.f, 0.f, 0.f, 0.f};
    f32x4 accP2 = {0.f, 0.f, 0.f, 0.f};
    f32x4 accT0 = {0.f, 0.f, 0.f, 0.f};
    f32x4 accT1 = {0.f, 0.f, 0.f, 0.f};
    f32x4 accT2 = {0.f, 0.f, 0.f, 0.f};
    f32x4 accT3 = {0.f, 0.f, 0.f, 0.f};
    f32x4 accT4 = {0.f, 0.f, 0.f, 0.f};

    const bf16x8* wb = (const bf16x8*)wtiles;
    do_chunk<0>(x0, x1, wb, lane, accS, accP0, accP1, accP2, accT0, accT1, accT2, accT3, accT4);
    do_chunk<1>(x0, x1, wb, lane, accS, accP0, accP1, accP2, accT0, accT1, accT2, accT3, accT4);
    do_chunk<2>(x0, x1, wb, lane, accS, accP0, accP1, accP2, accT0, accT1, accT2, accT3, accT4);
    do_chunk<3>(x0, x1, wb, lane, accS, accP0, accP1, accP2, accT0, accT1, accT2, accT3, accT4);
    do_chunk<4>(x0, x1, wb, lane, accS, accP0, accP1, accP2, accT0, accT1, accT2, accT3, accT4);
    do_chunk<5>(x0, x1, wb, lane, accS, accP0, accP1, accP2, accT0, accT1, accT2, accT3, accT4);
    do_chunk<6>(x0, x1, wb, lane, accS, accP0, accP1, accP2, accT0, accT1, accT2, accT3, accT4);
    do_chunk<7>(x0, x1, wb, lane, accS, accP0, accP1, accP2, accT0, accT1, accT2, accT3, accT4);
    do_chunk<8>(x0, x1, wb, lane, accS, accP0, accP1, accP2, accT0, accT1, accT2, accT3, accT4);

    // ---- epilogue: scatter to wave-private LDS image, coalesced write-out ----
    // C/D: col = lane&15 = output idx w (= m), row = q*4 + r = node-in-wave
#pragma unroll
    for (int r = 0; r < 4; ++r) {
        float* eb = sw + (q * 4 + r) * 144;
        eb[m]              = accS[r];
        eb[16 + 3 * m + 0] = accP0[r];
        eb[16 + 3 * m + 1] = accP1[r];
        eb[16 + 3 * m + 2] = accP2[r];
        eb[64 + 5 * m + 0] = accT0[r];
        eb[64 + 5 * m + 1] = accT1[r];
        eb[64 + 5 * m + 2] = accT2[r];
        eb[64 + 5 * m + 3] = accT3[r];
        eb[64 + 5 * m + 4] = accT4[r];
    }
    WAIT_LDS();   // same-wave scatter visible before read-back (wave-private)

    {
        const float4* ep4 = (const float4*)sw;
        float4* ob4 = (float4*)(out + waveNode * 144);
#pragma unroll
        for (int l = 0; l < 9; ++l)
            ob4[l * 64 + lane] = ep4[l * 64 + lane];   // 1024 B/instr contiguous
    }
}

extern "C" void kernel_launch(void* const* d_in, const int* in_sizes, int n_in,
                              void* d_out, int out_size, void* d_ws, size_t ws_size,
                              hipStream_t stream) {
    const float* feats = (const float*)d_in[0];
    const float* msgs  = (const float*)d_in[1];
    const float* w000  = (const float*)d_in[2];
    const float* w101  = (const float*)d_in[3];
    const float* w110  = (const float*)d_in[4];
    const float* w112  = (const float*)d_in[5];
    __bf16* wt = (__bf16*)d_ws;                 // 27*64*16 B = 27648 B
    float* out = (float*)d_out;

    const int n = in_sizes[0] / (4 * MUL);      // 131072 nodes

    prep_weights<<<(NTILE * 64 + 255) / 256, 256, 0, stream>>>(w000, w101, w110, w112, wt);
    tsq_kernel<<<n / 64, 256, 0, stream>>>(feats, msgs, wt, out);
}